// Round 9
// baseline (1190.510 us; speedup 1.0000x reference)
//
#include <hip/hip_runtime.h>

// DecoderLSTM (show-attend-tell) for MI355X — dataflow persistent version.
// B=64 T=32 F=512 L=196 E=512 H=512 A=512 V=10000, Tmax=31.
// Round-9 = Round-8 + bounded spin loops (hang-guard: a residual race now
// degrades to a visible wrong answer + profile instead of wedging the GPU).
// Phase A ELIMINATED.  4 independent 64-block groups; per step:
//   B (all 64): de = h@Wdec.T (coalesced matvec via WdecT), B1 tanh-dot on
//               49 LDS-pinned en_att rows -> bflag -> fgate matvec (hides
//               quartet wait) -> quartet poll -> softmax -> z  -> zflag
//   C (local<32): stages z(t) AND h(t-1), MFMA accumulates z@Wih2 + h@Whh
//               in one acc (+ec) ; LSTM pointwise -> h(t) -> hflag
// h is PARITY DOUBLE-BUFFERED (C writes buf[(t+1)&1]; readers use buf[t&1];
// inactive batches carry the staged old value forward).  Flags: sc1
// monotone epochs, stored unconditionally every step (deadlock-free).

typedef unsigned short ushort_t;
typedef __attribute__((ext_vector_type(8))) short short8;
typedef __attribute__((ext_vector_type(4))) float f32x4;

#define SPIN_CAP (1 << 22)  // hang-guard: break after ~4M polls

__device__ __forceinline__ float bf2f(ushort_t u) {
    unsigned x = ((unsigned)u) << 16;
    float f;
    __builtin_memcpy(&f, &x, 4);
    return f;
}
__device__ __forceinline__ ushort_t f2bf(float f) {
    unsigned x;
    __builtin_memcpy(&x, &f, 4);
    unsigned r = (x + 0x7fffu + ((x >> 16) & 1u)) >> 16;
    return (ushort_t)r;
}
__device__ __forceinline__ float sigmoidf_(float x) { return 1.f / (1.f + __expf(-x)); }
__device__ __forceinline__ float tanh_fast(float x) {
    float e = __expf(2.f * x);
    return 1.f - 2.f / (e + 1.f);
}
__device__ __forceinline__ float wred_sum(float v) {
    #pragma unroll
    for (int m = 32; m; m >>= 1) v += __shfl_xor(v, m, 64);
    return v;
}
__device__ __forceinline__ float wred_max(float v) {
    #pragma unroll
    for (int m = 32; m; m >>= 1) v = fmaxf(v, __shfl_xor(v, m, 64));
    return v;
}

// ---- agent-scope relaxed atomics: performed at LLC (sc1), no fences ----
__device__ __forceinline__ float aload_f(const float* p) {
    return __hip_atomic_load((float*)p, __ATOMIC_RELAXED, __HIP_MEMORY_SCOPE_AGENT);
}
__device__ __forceinline__ void astore_f(float* p, float v) {
    __hip_atomic_store(p, v, __ATOMIC_RELAXED, __HIP_MEMORY_SCOPE_AGENT);
}
__device__ __forceinline__ unsigned aload_u(const unsigned* p) {
    return __hip_atomic_load((unsigned*)p, __ATOMIC_RELAXED, __HIP_MEMORY_SCOPE_AGENT);
}
__device__ __forceinline__ void astore_u(unsigned* p, unsigned v) {
    __hip_atomic_store(p, v, __ATOMIC_RELAXED, __HIP_MEMORY_SCOPE_AGENT);
}
__device__ __forceinline__ int aload_i(const int* p) {
    return __hip_atomic_load((int*)p, __ATOMIC_RELAXED, __HIP_MEMORY_SCOPE_AGENT);
}
__device__ __forceinline__ void astore_i(int* p, int v) {
    __hip_atomic_store(p, v, __ATOMIC_RELAXED, __HIP_MEMORY_SCOPE_AGENT);
}

// exp2 scale: tanh(x) = 1 - 2/(2^(K*x)+1), K = 2*log2(e)
#define KEXP2 2.8853901817779268f

// ---- dtype detection (also zeroes the 1024 flag words) ----
__global__ void detect_kernel(const unsigned* __restrict__ feat_raw, int* __restrict__ flag,
                              int* __restrict__ flags) {
    int lane = threadIdx.x;
    #pragma unroll
    for (int i = 0; i < 16; ++i) flags[lane + i * 64] = 0;
    unsigned u = feat_raw[lane];
    unsigned e = (u >> 7) & 0xffu;
    bool bf_like = (e >= 105 && e <= 133);
    unsigned long long m = __ballot(bf_like);
    if (lane == 0) *flag = (__popcll(m) >= 40) ? 0 : 1;  // 1 -> fp32 inputs
}

#define NCVT 19
struct CvtArgs {
    const void* src[NCVT];
    void* dst[NCVT];
    int n[NCVT];
    int cub[NCVT + 1];  // cumulative 2048-elem block counts
};

__global__ __launch_bounds__(256) void convert_kernel(CvtArgs a, const int* __restrict__ flag) {
    int bx = blockIdx.x, ai = 0;
    while (bx >= a.cub[ai + 1]) ++ai;
    const int n = a.n[ai];
    const int base = (bx - a.cub[ai]) * 2048 + threadIdx.x * 8;
    if (base >= n) return;
    ushort_t* dst = (ushort_t*)a.dst[ai];
    if (*flag) {
        const float* s = (const float*)a.src[ai];
        #pragma unroll
        for (int i = 0; i < 8; ++i) {
            int idx = base + i;
            if (idx < n) dst[idx] = f2bf(s[idx]);
        }
    } else {
        const ushort_t* s = (const ushort_t*)a.src[ai];
        #pragma unroll
        for (int i = 0; i < 8; ++i) {
            int idx = base + i;
            if (idx < n) dst[idx] = s[idx];
        }
    }
}

// ---- WdecT[k][a] = Wdec[a][k] (64x64 LDS-tiled transpose) ----
__global__ __launch_bounds__(256) void transpose_wdec_kernel(const ushort_t* __restrict__ W3c,
                                                             ushort_t* __restrict__ WdT) {
    __shared__ ushort_t tile[64][65];
    const int ta = (blockIdx.x & 7) << 6;   // a-tile base
    const int tk = (blockIdx.x >> 3) << 6;  // k-tile base
    for (int i = threadIdx.x; i < 4096; i += 256) {
        int r = i >> 6, c = i & 63;
        tile[r][c] = W3c[(ta + r) * 512 + tk + c];
    }
    __syncthreads();
    for (int i = threadIdx.x; i < 4096; i += 256) {
        int r = i >> 6, c = i & 63;  // r = k-local, c = a-local
        WdT[(tk + r) * 512 + ta + c] = tile[c][r];
    }
}

// ---- gather needed embedding rows -> bf16 [31*64, 512] ----
__global__ __launch_bounds__(256) void embrows_kernel(const void* __restrict__ Wemb,
                                                      const int* __restrict__ captions,
                                                      const int* __restrict__ flag,
                                                      ushort_t* __restrict__ emb_c) {
    const int tb = blockIdx.x;  // t*64 + b
    const int t = tb >> 6, b = tb & 63;
    const int cap = captions[b * 32 + t];
    const int e0 = threadIdx.x;
    if (*flag) {
        const float* s = (const float*)Wemb + cap * 512;
        emb_c[tb * 512 + e0] = f2bf(s[e0]);
        emb_c[tb * 512 + e0 + 256] = f2bf(s[e0 + 256]);
    } else {
        const ushort_t* s = (const ushort_t*)Wemb + cap * 512;
        emb_c[tb * 512 + e0] = s[e0];
        emb_c[tb * 512 + e0 + 256] = s[e0 + 256];
    }
}

// ---- w2[a] = -2*wf[a]; w2[512] = sum(wf)+b_full ----
__global__ void prepw2_kernel(const ushort_t* __restrict__ wf, const ushort_t* __restrict__ bfc,
                              float* __restrict__ w2) {
    int tid = threadIdx.x;  // 512
    float w = bf2f(wf[tid]);
    w2[tid] = -2.f * w;
    float s = wred_sum(w);
    __shared__ float r8[8];
    if ((tid & 63) == 0) r8[tid >> 6] = s;
    __syncthreads();
    if (tid == 0) {
        float tot = r8[0] + r8[1] + r8[2] + r8[3] + r8[4] + r8[5] + r8[6] + r8[7];
        w2[512] = tot + bf2f(bfc[0]);
    }
}

// ---- 64x64 MFMA tile, K=512, 256 threads (4 waves), bf16 in / fp32 acc ----
template <class AROW, class BROW, class EPI>
__device__ __forceinline__ void gemm_tile(AROW arow, BROW brow, EPI epi) {
    __shared__ __align__(16) ushort_t As[64][40];
    __shared__ __align__(16) ushort_t Bs[64][40];
    const int tid = threadIdx.x;
    const int row = tid >> 2, ks = (tid & 3) << 3;
    const int wave = tid >> 6, lane = tid & 63;
    const int quad = lane >> 4, l15 = lane & 15;
    f32x4 acc[4];
    #pragma unroll
    for (int s = 0; s < 4; ++s) acc[s] = (f32x4){0.f, 0.f, 0.f, 0.f};
    const ushort_t* ap = arow(row);
    const ushort_t* bp = brow(row);
    for (int k0 = 0; k0 < 512; k0 += 32) {
        short8 av = {0, 0, 0, 0, 0, 0, 0, 0};
        short8 bv = {0, 0, 0, 0, 0, 0, 0, 0};
        if (ap) av = *(const short8*)(ap + k0 + ks);
        if (bp) bv = *(const short8*)(bp + k0 + ks);
        __syncthreads();
        *(short8*)&As[row][ks] = av;
        *(short8*)&Bs[row][ks] = bv;
        __syncthreads();
        short8 af = *(const short8*)&As[(wave << 4) + l15][quad << 3];
        #pragma unroll
        for (int s = 0; s < 4; ++s) {
            short8 bfr = *(const short8*)&Bs[(s << 4) + l15][quad << 3];
            acc[s] = __builtin_amdgcn_mfma_f32_16x16x32_bf16(af, bfr, acc[s], 0, 0, 0);
        }
    }
    epi((wave << 4) + (quad << 2), l15, acc);
}

// ---- mean over L of features [B, F, L] -> bf16 [B, F] ----
__global__ __launch_bounds__(256) void mean_kernel(const ushort_t* __restrict__ features,
                                                   ushort_t* __restrict__ mean_bf) {
    const int b = blockIdx.x;
    const int wave = threadIdx.x >> 6, lane = threadIdx.x & 63;
    const ushort_t* fb = features + b * 512 * 196;
    for (int f = wave; f < 512; f += 4) {
        const ushort_t* r = fb + f * 196;
        float s = bf2f(r[lane]) + bf2f(r[lane + 64]) + bf2f(r[lane + 128]);
        if (lane < 4) s += bf2f(r[lane + 192]);
        s = wred_sum(s);
        if (lane == 0) mean_bf[b * 512 + f] = f2bf(s * (1.f / 196.f));
    }
}

// ---- h0 / c0 ----
__global__ __launch_bounds__(256) void init_kernel(
    const ushort_t* __restrict__ mean_bf, const ushort_t* __restrict__ Winh,
    const ushort_t* __restrict__ binh, const ushort_t* __restrict__ Winc,
    const ushort_t* __restrict__ binc, ushort_t* __restrict__ h_bf,
    float* __restrict__ cbuf) {
    const int n0 = blockIdx.x << 6;
    gemm_tile(
        [&](int r) { return mean_bf + r * 512; },
        [&](int r) {
            int n = n0 + r;
            return (n < 512) ? (Winh + n * 512) : (Winc + (n - 512) * 512);
        },
        [&](int mb, int l15, const f32x4* acc) {
            #pragma unroll
            for (int s = 0; s < 4; ++s) {
                int n = n0 + (s << 4) + l15;
                #pragma unroll
                for (int r = 0; r < 4; ++r) {
                    int b = mb + r;
                    if (n < 512)
                        h_bf[b * 512 + n] = f2bf(acc[s][r] + bf2f(binh[n]));
                    else
                        cbuf[b * 512 + (n - 512)] = acc[s][r] + bf2f(binc[n - 512]);
                }
            }
        });
}

// ---- en_att = feat_r @ W_enc.T + b_enc -> bf16 [12544, 512] ----
__global__ __launch_bounds__(256) void enatt_kernel(const ushort_t* __restrict__ feat,
                                                    const ushort_t* __restrict__ Wenc,
                                                    const ushort_t* __restrict__ benc,
                                                    ushort_t* __restrict__ en_att) {
    const int m0 = blockIdx.y << 6, n0 = blockIdx.x << 6;
    gemm_tile(
        [&](int r) { return feat + (m0 + r) * 512; },
        [&](int r) { return Wenc + (n0 + r) * 512; },
        [&](int mb, int l15, const f32x4* acc) {
            #pragma unroll
            for (int s = 0; s < 4; ++s) {
                int n = n0 + (s << 4) + l15;
                float bias = bf2f(benc[n]);
                #pragma unroll
                for (int r = 0; r < 4; ++r) {
                    int m = m0 + mb + r;
                    en_att[m * 512 + n] = f2bf(acc[s][r] + bias);
                }
            }
        });
}

// ---- ec[t,b,j] = emb_row @ W_ih[:, :512].T + b_ih + b_hh -> fp32 ----
__global__ __launch_bounds__(256) void ec_kernel(const ushort_t* __restrict__ emb_c,
                                                 const ushort_t* __restrict__ Wih,
                                                 const ushort_t* __restrict__ bih,
                                                 const ushort_t* __restrict__ bhh,
                                                 float* __restrict__ ec) {
    const int t = blockIdx.y, n0 = blockIdx.x << 6;
    gemm_tile(
        [&](int r) { return emb_c + (t * 64 + r) * 512; },
        [&](int r) { return Wih + (n0 + r) * 1024; },
        [&](int mb, int l15, const f32x4* acc) {
            #pragma unroll
            for (int s = 0; s < 4; ++s) {
                int j = n0 + (s << 4) + l15;
                float bias = bf2f(bih[j]) + bf2f(bhh[j]);
                #pragma unroll
                for (int r = 0; r < 4; ++r) {
                    int b = mb + r;
                    ec[(t * 64 + b) * 2048 + j] = acc[s][r] + bias;
                }
            }
        });
}

struct LoopArgs {
    const ushort_t* W3c;     // [3072][512] = [Wdec; Wfb; Whh]
    const ushort_t* WdT;     // [512 k][512 a] = Wdec^T
    const ushort_t* bdec;
    const ushort_t* bfb;
    const ushort_t* en_att;  // [12544][512]
    const ushort_t* feat;    // [64][196][512]
    const ushort_t* Wih;     // [2048][1024]
    const float* w2;         // [513]: -2*wf, [512]=sum(wf)+b_full
    const float* ec;         // [1984][2048]
    const int* lengths;
    const int* flag;
    ushort_t* h_bf;          // 2 x [64][512] parity buffers
    ushort_t* z_bf;
    ushort_t* H_all;
    float* cbuf;
    float* fullv;            // [64][196]
    void* out_base;
    int* flags;              // [4][256]: [0:32) h, [64:128) z, [128:192) bq
};

// Persistent dataflow loop. 256 blocks x 512 threads, 1 block/CU.
__global__ __launch_bounds__(512, 2) void loop_kernel(LoopArgs A) {
    const int blk = blockIdx.x, tid = threadIdx.x;
    const int wave = tid >> 6, lane = tid & 63;
    const int quad = lane >> 4, l15 = lane & 15;
    const int g = blk >> 6, local = blk & 63;
    int* fbase = A.flags + g * 256;

    __shared__ __align__(16) ushort_t enS[49 * 512];    // en_att slice (bB, 49 l's)
    __shared__ __align__(16) ushort_t ftS[196 * 128];   // feat slice (bB, 128 f's)
    __shared__ __align__(16) ushort_t AsL[32][520];     // C: z rows 0-15, h rows 16-31
    __shared__ float smem[4096];                        // B de-partials | z part | C acc
    __shared__ float hS[512];                           // B: h(t-1) as f32
    __shared__ float deS[512];                          // B: K*(de+bdec)
    __shared__ float fgS[128];                          // B: sigmoid fgate quarter
    __shared__ float fullS[200];                        // B: alpha
    __shared__ float red8[16];

    const int f32o = *A.flag;
    const int b0 = g << 4;                   // group's first batch
    const int Tg = A.lengths[b0] - 1;        // group's max dec_len (sorted desc)

    const int bB = b0 + (local >> 2);        // B role batch
    const int qB = local & 3;                // B role quarter
    const int lenB = A.lengths[bB];
    const bool roleC = local < 32;
    const int dtC = local;                   // C role dim-tile (if roleC)

    unsigned* h_u32 = (unsigned*)A.h_bf;     // parity buffers: + (t&1)<<14
    unsigned* z_u32 = (unsigned*)A.z_bf;

    float w2r[8];
    {
        f32x4 w0 = *(const f32x4*)(A.w2 + lane * 8);
        f32x4 w1 = *(const f32x4*)(A.w2 + lane * 8 + 4);
        w2r[0] = w0[0]; w2r[1] = w0[1]; w2r[2] = w0[2]; w2r[3] = w0[3];
        w2r[4] = w1[0]; w2r[5] = w1[1]; w2r[6] = w1[2]; w2r[7] = w1[3];
    }
    const float fullc = A.w2[512];

    // one-time LDS pinning of this block's attention slices (B role)
    {
        const short8* src = (const short8*)(A.en_att + ((size_t)bB * 196 + qB * 49) * 512);
        short8* dst = (short8*)enS;
        for (int i = tid; i < 49 * 64; i += 512) dst[i] = src[i];
        const ushort_t* fsrc = A.feat + (size_t)bB * 100352 + qB * 128;
        short8* fdst = (short8*)ftS;
        for (int i = tid; i < 196 * 16; i += 512) {
            int l = i >> 4, c = i & 15;
            fdst[i] = *(const short8*)(fsrc + l * 512 + c * 8);
        }
    }
    __syncthreads();

    for (int t = 0; t < Tg; ++t) {
        const bool act = (lenB - 1) > t;
        const size_t aoff = 19840000ull + ((size_t)bB * 31 + t) * 196;

        // ================= Phase B part 1: de matvec + B1 =================
        if (act) {
            if (wave == 0 && t > 0) {        // wait h(t-1) from all 32 C-blocks
                const int* fp = fbase + (lane & 31);
                int spins = 0;
                for (;;) {
                    if (__all(aload_i(fp) >= t)) break;
                    if (++spins > SPIN_CAP) break;   // hang-guard
                    __builtin_amdgcn_s_sleep(1);
                }
                asm volatile("" ::: "memory");
            }
            __syncthreads();
            // load h(t-1) for bB -> hS (f32)
            {
                const unsigned* hsrc = h_u32 + ((t & 1) << 14) + bB * 256;
                if (tid < 256) {
                    unsigned v = aload_u(hsrc + tid);
                    hS[tid * 2] = bf2f((ushort_t)(v & 0xffffu));
                    hS[tid * 2 + 1] = bf2f((ushort_t)(v >> 16));
                }
            }
            __syncthreads();
            // de = h @ Wdec.T  via WdecT (coalesced: wave reads contiguous 1KB/instr)
            {
                float p[8];
                #pragma unroll
                for (int j = 0; j < 8; ++j) p[j] = 0.f;
                const ushort_t* wt = A.WdT + (wave << 6) * 512 + (lane << 3);
                #pragma unroll 4
                for (int i = 0; i < 64; ++i) {
                    short8 wv = *(const short8*)(wt + i * 512);
                    float hk = hS[(wave << 6) + i];
                    #pragma unroll
                    for (int j = 0; j < 8; ++j)
                        p[j] = fmaf(bf2f((ushort_t)wv[j]), hk, p[j]);
                }
                #pragma unroll
                for (int j = 0; j < 8; ++j)
                    smem[(wave << 9) + (lane << 3) + j] = p[j];
            }
            __syncthreads();
            {
                float dsum = 0.f;
                #pragma unroll
                for (int q = 0; q < 8; ++q) dsum += smem[(q << 9) + tid];
                deS[tid] = (dsum + bf2f(A.bdec[tid])) * KEXP2;
            }
            __syncthreads();
            // B1: full for own 49 pinned rows
            {
                float dkr[8];
                #pragma unroll
                for (int j = 0; j < 8; ++j) dkr[j] = deS[lane * 8 + j];
                for (int i = wave; i < 49; i += 8) {
                    short8 ev = *(const short8*)(enS + i * 512 + lane * 8);
                    float acc = 0.f;
                    #pragma unroll
                    for (int j = 0; j < 8; ++j) {
                        float e2 = __builtin_amdgcn_exp2f(
                            fmaf(bf2f((ushort_t)ev[j]), KEXP2, dkr[j]));
                        acc = fmaf(w2r[j], __builtin_amdgcn_rcpf(e2 + 1.f), acc);
                    }
                    acc = wred_sum(acc);
                    if (lane == 0)
                        astore_f(A.fullv + bB * 196 + qB * 49 + i, acc + fullc);
                }
            }
        }
        asm volatile("s_waitcnt vmcnt(0)" ::: "memory");
        __syncthreads();
        if (tid == 0) astore_i(fbase + 128 + local, t + 1);

        // ====== Phase B part 2: fgate (hides quartet wait) + softmax + z ======
        if (act) {
            // fgate partials for own f-quarter (overlaps quartet settle)
            {
                const int fl_ = tid >> 2, kq_ = tid & 3;
                const ushort_t* wr = A.W3c + (512 + (qB << 7) + fl_) * 512 + (kq_ << 7);
                float a2 = 0.f;
                #pragma unroll 4
                for (int k = 0; k < 128; k += 8) {
                    short8 wv = *(const short8*)(wr + k);
                    #pragma unroll
                    for (int j = 0; j < 8; ++j)
                        a2 = fmaf(bf2f((ushort_t)wv[j]), hS[(kq_ << 7) + k + j], a2);
                }
                smem[tid] = a2;
            }
            if (wave == 0) {                 // quartet mini-sync (4 bflags)
                const int* fp = fbase + 128 + (local & ~3) + (lane & 3);
                int spins = 0;
                for (;;) {
                    if (__all(aload_i(fp) >= t + 1)) break;
                    if (++spins > SPIN_CAP) break;   // hang-guard
                    __builtin_amdgcn_s_sleep(1);
                }
                asm volatile("" ::: "memory");
            }
            __syncthreads();
            if (tid < 128)
                fgS[tid] = sigmoidf_(smem[tid << 2] + smem[(tid << 2) | 1] +
                                     smem[(tid << 2) | 2] + smem[(tid << 2) | 3] +
                                     bf2f(A.bfb[(qB << 7) + tid]));
            float v = (tid < 196) ? aload_f(A.fullv + bB * 196 + tid) : -1e30f;
            float wm = wred_max(v);
            if (lane == 0) red8[wave] = wm;
            __syncthreads();
            float mx = fmaxf(fmaxf(fmaxf(red8[0], red8[1]), fmaxf(red8[2], red8[3])),
                             fmaxf(fmaxf(red8[4], red8[5]), fmaxf(red8[6], red8[7])));
            float e = (tid < 196) ? __expf(v - mx) : 0.f;
            float sw = wred_sum(e);
            if (lane == 0) red8[8 + wave] = sw;
            __syncthreads();
            float tot = red8[8] + red8[9] + red8[10] + red8[11] +
                        red8[12] + red8[13] + red8[14] + red8[15];
            float inv = 1.f / tot;
            float a = e * inv;
            if (tid < 196) fullS[tid] = a;
            __syncthreads();
            const int fl = tid & 127, gq = tid >> 7;
            float zacc = 0.f;
            #pragma unroll 4
            for (int l = gq; l < 196; l += 4)
                zacc = fmaf(fullS[l], bf2f(ftS[l * 128 + fl]), zacc);
            smem[256 + (gq << 7) + fl] = zacc;
            __syncthreads();
            if (tid < 64) {
                const int f0l = tid << 1;
                float z0 = smem[256 + f0l] + smem[384 + f0l] +
                           smem[512 + f0l] + smem[640 + f0l];
                float z1 = smem[257 + f0l] + smem[385 + f0l] +
                           smem[513 + f0l] + smem[641 + f0l];
                z0 *= fgS[f0l];
                z1 *= fgS[f0l + 1];
                unsigned zp = (unsigned)f2bf(z0) | ((unsigned)f2bf(z1) << 16);
                astore_u(z_u32 + bB * 256 + (qB << 6) + tid, zp);
            }
        }
        asm volatile("s_waitcnt vmcnt(0)" ::: "memory");
        __syncthreads();
        if (tid == 0) astore_i(fbase + 64 + local, t + 1);
        // alpha output (off the critical path, after zflag)
        if (qB == 0 && tid < 196) {
            if (act) {
                if (f32o) ((float*)A.out_base)[aoff + tid] = fullS[tid];
                else ((ushort_t*)A.out_base)[aoff + tid] = f2bf(fullS[tid]);
            } else {
                if (f32o) ((float*)A.out_base)[aoff + tid] = 0.f;
                else ((ushort_t*)A.out_base)[aoff + tid] = 0;
            }
        }

        // ==== Phase C: gates = z@Wih2 + h_prev@Whh + ec ; LSTM pointwise ====
        if (roleC) {
            if (wave == 0) {   // wait all 64 zflags
                const int* zp = fbase + 64 + lane;
                int spins = 0;
                for (;;) {
                    if (__all(aload_i(zp) >= t + 1)) break;
                    if (++spins > SPIN_CAP) break;   // hang-guard
                    __builtin_amdgcn_s_sleep(1);
                }
                asm volatile("" ::: "memory");
            }
            __syncthreads();
            // prefetch ec before staging/MFMA
            float pe[8];
            #pragma unroll
            for (int k = 0; k < 8; ++k) pe[k] = 0.f;
            if (tid < 128) {
                const int bl = tid >> 3, p = tid & 7;
                const int bE = b0 + bl;
                const int dimE = (dtC << 4) + (p << 1);
                const int eb = (t * 64 + bE) * 2048;
                pe[0] = A.ec[eb + dimE];         pe[1] = A.ec[eb + dimE + 1];
                pe[2] = A.ec[eb + 512 + dimE];   pe[3] = A.ec[eb + 512 + dimE + 1];
                pe[4] = A.ec[eb + 1024 + dimE];  pe[5] = A.ec[eb + 1024 + dimE + 1];
                pe[6] = A.ec[eb + 1536 + dimE];  pe[7] = A.ec[eb + 1536 + dimE + 1];
            }
            // stage z(t) rows -> AsL[0..15], h(t-1) rows -> AsL[16..31]
            {
                const unsigned* hsrc = h_u32 + ((t & 1) << 14);
                for (int i = tid; i < 4096; i += 512) {
                    int r = i >> 8, c = i & 255;
                    *(unsigned*)&AsL[r][c << 1] = aload_u(z_u32 + ((b0 + r) << 8) + c);
                    *(unsigned*)&AsL[16 + r][c << 1] = aload_u(hsrc + ((b0 + r) << 8) + c);
                }
            }
            __syncthreads();
            const int gw = wave & 3, kh = wave >> 2;
            const int j = (gw << 9) + (dtC << 4) + l15;
            const ushort_t* brz = A.Wih + j * 1024 + 512 + (kh << 8) + (quad << 3);
            const ushort_t* brh = A.W3c + (1024 + j) * 512 + (kh << 8) + (quad << 3);
            const ushort_t* arz = &AsL[l15][(kh << 8) + (quad << 3)];
            const ushort_t* arh = &AsL[16 + l15][(kh << 8) + (quad << 3)];
            f32x4 acc = {0.f, 0.f, 0.f, 0.f};
            #pragma unroll
            for (int k0 = 0; k0 < 256; k0 += 32) {
                acc = __builtin_amdgcn_mfma_f32_16x16x32_bf16(
                    *(const short8*)(arz + k0), *(const short8*)(brz + k0), acc, 0, 0, 0);
                acc = __builtin_amdgcn_mfma_f32_16x16x32_bf16(
                    *(const short8*)(arh + k0), *(const short8*)(brh + k0), acc, 0, 0, 0);
            }
            #pragma unroll
            for (int r = 0; r < 4; ++r)
                smem[(wave << 8) + (((quad << 2) + r) << 4) + l15] = acc[r];
            __syncthreads();
            float cn0 = 0.f, cn1 = 0.f;
            unsigned hpw = 0;
            bool activeB = false;
            int bQ = 0, dimQ = 0;
            if (tid < 128) {
                const int bl = tid >> 3, p = tid & 7;
                bQ = b0 + bl;
                dimQ = (dtC << 4) + (p << 1);
                const int i0 = (bl << 4) + (p << 1);
                float ig0 = smem[i0] + smem[1024 + i0] + pe[0];
                float ig1 = smem[i0 + 1] + smem[1025 + i0] + pe[1];
                float fg0 = smem[256 + i0] + smem[1280 + i0] + pe[2];
                float fg1 = smem[257 + i0] + smem[1281 + i0] + pe[3];
                float gg0 = smem[512 + i0] + smem[1536 + i0] + pe[4];
                float gg1 = smem[513 + i0] + smem[1537 + i0] + pe[5];
                float og0 = smem[768 + i0] + smem[1792 + i0] + pe[6];
                float og1 = smem[769 + i0] + smem[1793 + i0] + pe[7];
                float co0 = A.cbuf[bQ * 512 + dimQ];
                float co1 = A.cbuf[bQ * 512 + dimQ + 1];
                cn0 = sigmoidf_(fg0) * co0 + sigmoidf_(ig0) * tanh_fast(gg0);
                float hn0 = sigmoidf_(og0) * tanh_fast(cn0);
                cn1 = sigmoidf_(fg1) * co1 + sigmoidf_(ig1) * tanh_fast(gg1);
                float hn1 = sigmoidf_(og1) * tanh_fast(cn1);
                activeB = (A.lengths[bQ] - 1) > t;
                unsigned newp = (unsigned)f2bf(hn0) | ((unsigned)f2bf(hn1) << 16);
                unsigned oldp = *(const unsigned*)&AsL[16 + bl][dimQ];
                hpw = activeB ? newp : oldp;   // carry frozen h forward
                astore_u(h_u32 + (((t + 1) & 1) << 14) + bQ * 256 + (dimQ >> 1), hpw);
            }
            asm volatile("s_waitcnt vmcnt(0)" ::: "memory");
            __syncthreads();
            if (tid == 0) astore_i(fbase + dtC, t + 1);
            // off-critical-path stores after the flag
            if (tid < 128) {
                *(unsigned*)&A.H_all[(t * 64 + bQ) * 512 + dimQ] = hpw;
                if (activeB) {
                    A.cbuf[bQ * 512 + dimQ] = cn0;
                    A.cbuf[bQ * 512 + dimQ + 1] = cn1;
                }
            }
        }
    }

    // post-loop: zero remaining alpha rows for this group's batches
    if (qB == 0) {
        for (int t = Tg; t < 31; ++t) {
            if (tid < 196) {
                const size_t aoff2 = 19840000ull + ((size_t)bB * 31 + t) * 196;
                if (f32o) ((float*)A.out_base)[aoff2 + tid] = 0.f;
                else ((ushort_t*)A.out_base)[aoff2 + tid] = 0;
            }
        }
    }
}

// ---- preds = H_all @ W_out.T + b_out, ragged-masked ----
// grid (31, 157): t varies fastest so 31 blocks sharing a Wout tile are
// adjacent in dispatch order -> tile stays in L2/LLC.
__global__ __launch_bounds__(256) void preds_kernel(
    const ushort_t* __restrict__ H_all, const ushort_t* __restrict__ Wout,
    const ushort_t* __restrict__ bout, const int* __restrict__ lengths,
    const int* __restrict__ flag, void* __restrict__ out_base) {
    const int t = blockIdx.x, n0 = blockIdx.y << 6;
    const int f32o = *flag;
    gemm_tile(
        [&](int r) { return H_all + (t * 64 + r) * 512; },
        [&](int r) -> const ushort_t* {
            int n = n0 + r;
            return (n < 10000) ? (Wout + n * 512) : (const ushort_t*)nullptr;
        },
        [&](int mb, int l15, const f32x4* acc) {
            #pragma unroll
            for (int s = 0; s < 4; ++s) {
                int n = n0 + (s << 4) + l15;
                if (n >= 10000) continue;
                float bias = bf2f(bout[n]);
                #pragma unroll
                for (int r = 0; r < 4; ++r) {
                    int b = mb + r;
                    bool act = lengths[b] > t + 1;
                    float val = act ? (acc[s][r] + bias) : 0.f;
                    size_t off = (size_t)b * 310000 + t * 10000 + n;
                    if (f32o) ((float*)out_base)[off] = val;
                    else ((ushort_t*)out_base)[off] = act ? f2bf(val) : (ushort_t)0;
                }
            }
        });
}

extern "C" void kernel_launch(void* const* d_in, const int* in_sizes, int n_in,
                              void* d_out, int out_size, void* d_ws, size_t ws_size,
                              hipStream_t stream) {
    const void* features = d_in[0];
    const int* captions = (const int*)d_in[1];
    const int* lengths = (const int*)d_in[2];
    const void* W_emb = d_in[3];

    char* ws = (char*)d_ws;
    size_t o = 0;
    auto alloc = [&](size_t bytes) {
        size_t r = o;
        o += (bytes + 255) & ~(size_t)255;
        return r;
    };
    // canonical bf16 copies
    ushort_t* feat_c  = (ushort_t*)(ws + alloc(6422528ull * 2));
    ushort_t* Wenc_c  = (ushort_t*)(ws + alloc(262144ull * 2));
    ushort_t* benc_c  = (ushort_t*)(ws + alloc(512 * 2));
    ushort_t* W3c     = (ushort_t*)(ws + alloc(3072ull * 512 * 2));  // [Wdec;Wfb;Whh]
    ushort_t* WdT     = (ushort_t*)(ws + alloc(262144ull * 2));      // Wdec^T
    ushort_t* bdec_c  = (ushort_t*)(ws + alloc(512 * 2));
    ushort_t* wfull_c = (ushort_t*)(ws + alloc(512 * 2));
    ushort_t* bfull_c = (ushort_t*)(ws + alloc(2));
    ushort_t* bfb_c   = (ushort_t*)(ws + alloc(512 * 2));
    ushort_t* Wih_c   = (ushort_t*)(ws + alloc(2097152ull * 2));
    ushort_t* bih_c   = (ushort_t*)(ws + alloc(2048 * 2));
    ushort_t* bhh_c   = (ushort_t*)(ws + alloc(2048 * 2));
    ushort_t* Wout_c  = (ushort_t*)(ws + alloc(5120000ull * 2));
    ushort_t* bout_c  = (ushort_t*)(ws + alloc(10000 * 2));
    ushort_t* Winh_c  = (ushort_t*)(ws + alloc(262144ull * 2));
    ushort_t* binh_c  = (ushort_t*)(ws + alloc(512 * 2));
    ushort_t* Winc_c  = (ushort_t*)(ws + alloc(262144ull * 2));
    ushort_t* binc_c  = (ushort_t*)(ws + alloc(512 * 2));
    ushort_t* emb_c   = (ushort_t*)(ws + alloc(1984ull * 512 * 2));
    // intermediates
    ushort_t* en_att  = (ushort_t*)(ws + alloc(12544ull * 512 * 2));
    float*    ec      = (float*)(ws + alloc(1984ull * 2048 * 4));
    ushort_t* H_all   = (ushort_t*)(ws + alloc(1984ull * 512 * 2));
    ushort_t* h_bf    = (ushort_t*)(ws + alloc(2ull * 64 * 512 * 2));  // parity x2
    float*    cbuf    = (float*)(ws + alloc(64 * 512 * 4));
    ushort_t* z_bf    = (ushort_t*)(ws + alloc(64 * 512 * 2));
    ushort_t* mean_bf = (ushort_t*)(ws + alloc(64 * 512 * 2));
    float*    fullv   = (float*)(ws + alloc(64 * 196 * 4));
    float*    w2buf   = (float*)(ws + alloc(513 * 4));
    int*      flag    = (int*)(ws + alloc(256));
    int*      flags   = (int*)(ws + alloc(1024 * 4));

    detect_kernel<<<1, 64, 0, stream>>>((const unsigned*)features, flag, flags);

    CvtArgs ca;
    const void* srcs[NCVT] = {features, d_in[4], d_in[5], d_in[6], d_in[7], d_in[8],
                              d_in[9], d_in[10], d_in[11], d_in[12], d_in[13], d_in[14],
                              d_in[15], d_in[16], d_in[17], d_in[18], d_in[19], d_in[20],
                              d_in[21]};
    void* dsts[NCVT] = {feat_c, Wenc_c, benc_c, W3c /*Wdec*/, bdec_c, wfull_c, bfull_c,
                        W3c + 262144 /*Wfb*/, bfb_c, Wih_c, W3c + 524288 /*Whh*/,
                        bih_c, bhh_c, Wout_c, bout_c, Winh_c, binh_c, Winc_c, binc_c};
    int ns[NCVT] = {6422528, 262144, 512, 262144, 512, 512, 1, 262144, 512,
                    2097152, 1048576, 2048, 2048, 5120000, 10000, 262144, 512,
                    262144, 512};
    ca.cub[0] = 0;
    for (int i = 0; i < NCVT; ++i) {
        ca.src[i] = srcs[i];
        ca.dst[i] = dsts[i];
        ca.n[i] = ns[i];
        ca.cub[i + 1] = ca.cub[i] + (ns[i] + 2047) / 2048;
    }
    convert_kernel<<<ca.cub[NCVT], 256, 0, stream>>>(ca, flag);
    transpose_wdec_kernel<<<64, 256, 0, stream>>>(W3c, WdT);
    embrows_kernel<<<1984, 256, 0, stream>>>(W_emb, captions, flag, emb_c);
    prepw2_kernel<<<1, 512, 0, stream>>>(wfull_c, bfull_c, w2buf);

    mean_kernel<<<64, 256, 0, stream>>>(feat_c, mean_bf);
    init_kernel<<<16, 256, 0, stream>>>(mean_bf, Winh_c, binh_c, Winc_c, binc_c,
                                        h_bf, cbuf);
    enatt_kernel<<<dim3(8, 196), 256, 0, stream>>>(feat_c, Wenc_c, benc_c, en_att);
    ec_kernel<<<dim3(32, 31), 256, 0, stream>>>(emb_c, Wih_c, bih_c, bhh_c, ec);

    LoopArgs la;
    la.W3c = W3c; la.WdT = WdT; la.bdec = bdec_c; la.bfb = bfb_c;
    la.en_att = en_att; la.feat = feat_c; la.Wih = Wih_c;
    la.w2 = w2buf; la.ec = ec; la.lengths = lengths; la.flag = flag;
    la.h_bf = h_bf; la.z_bf = z_bf; la.H_all = H_all;
    la.cbuf = cbuf; la.fullv = fullv;
    la.out_base = d_out; la.flags = flags;
    loop_kernel<<<256, 512, 0, stream>>>(la);

    preds_kernel<<<dim3(31, 157), 256, 0, stream>>>(H_all, Wout_c, bout_c, lengths,
                                                    flag, d_out);
}